// Round 6
// baseline (279.829 us; speedup 1.0000x reference)
//
#include <hip/hip_runtime.h>
#include <cstdint>

// ---------------- ws layout (bytes) ----------------
// fc1_wT  @ 4096     : [800][256] f32 (zero-padded k>=784)   819200 B
// fc2_wT  @ 823296   : [256][128] f32                        131072 B
// h3T     @ 954368   : [800][4096] f32 (rows>=784 unused)  13107200 B
// h1T     @ 14061568 : [256][4096] f32                      4194304 B
// h2T     @ 18255872 : [128][4096] f32                      2097152 B
//   NOTE: conv tables live at OFF_H2T during {prep, conv_stack}; fc2 later
//   overwrites the region with h2T. Lifetimes are disjoint (same stream).
#define OFF_W1T   4096
#define OFF_W2T   823296
#define OFF_H3T   954368
#define OFF_H1T   14061568
#define OFF_H2T   18255872

// table word offsets (int32 words, base = ws + OFF_H2T)
#define TW_WB1    0      // [32]  conv1 weight bits (9 taps in bits 0..8)
#define TW_W2     32     // [576] conv2 bits: [oc64][tap9], 32 ic bits
#define TW_W3     608    // [288] conv3 bits: [oc16][tap9][word2], 32 ic bits
#define TW_CORR2  896    // [16][64] border correction, conv2
#define TW_CORR3  1920   // [16][16] border correction, conv3  (contig w/ CORR2)
#define TW_TLE1   2176   // [32] conv1 interior: bit <=> Smin <= tle1
#define TW_TGE1   2208   // [32] conv1 border:   bit <=> Dmax >= tge1
#define TW_TLE2   2240   // [64] conv2 interior: bit <=> Smin <= tle2
#define TW_TGE2   2304   // [64] conv2 border:   bit <=> Dmax >= tge2

__device__ __forceinline__ int imin2(int a, int b) { return a < b ? a : b; }
__device__ __forceinline__ int imax2(int a, int b) { return a > b ? a : b; }

// ---------------- prep ------------------------------------------------------
// block 0: tables. blocks 1..52: fc1_w transpose (64x64 LDS tiles, coalesced
// both sides). blocks 53..60: fc2_w transpose.
__global__ __launch_bounds__(256) void prep(
    const float* __restrict__ w1, const float* __restrict__ b1,
    const float* __restrict__ w2, const float* __restrict__ b2,
    const float* __restrict__ w3,
    const float* __restrict__ fc1_w, const float* __restrict__ fc2_w,
    int* __restrict__ tab, float* __restrict__ w1T, float* __restrict__ w2T) {
    int t = threadIdx.x;
    uint32_t* utab = (uint32_t*)tab;
    if (blockIdx.x == 0) {
        if (t < 32) {
            uint32_t b = 0;
            for (int k = 0; k < 9; ++k) b |= (w1[t * 9 + k] > 0.f ? 1u : 0u) << k;
            utab[TW_WB1 + t] = b;
            tab[TW_TLE1 + t] = (int)floorf((9.f + b1[t]) * 0.5f);
            tab[TW_TGE1 + t] = (int)floorf(-b1[t]) + 1;
        }
        if (t >= 32 && t < 96) {
            int oc = t - 32;
            tab[TW_TLE2 + oc] = (int)floorf((288.f + b2[oc]) * 0.5f);
            tab[TW_TGE2 + oc] = (int)floorf(-b2[oc]) + 1;
        }
        for (int idx = t; idx < 576; idx += 256) {
            int oc = idx / 9, tap = idx % 9;
            int kh = tap / 3, kw = tap % 3;
            uint32_t b = 0;
            for (int ic = 0; ic < 32; ++ic)
                b |= (w2[((oc * 32 + ic) * 3 + kh) * 3 + kw] > 0.f ? 1u : 0u) << ic;
            utab[TW_W2 + idx] = b;
        }
        for (int idx = t; idx < 288; idx += 256) {
            int oc = idx / 18, rem = idx % 18;
            int tap = rem >> 1, word = rem & 1;
            int kh = tap / 3, kw = tap % 3;
            uint32_t b = 0;
            for (int ic = 0; ic < 32; ++ic)
                b |= (w3[((oc * 64 + ic + 32 * word) * 3 + kh) * 3 + kw] > 0.f ? 1u : 0u) << ic;
            utab[TW_W3 + idx] = b;
        }
        __syncthreads();   // packed words -> visible for correction pass
        for (int idx = t; idx < 1024; idx += 256) {
            int pat = idx >> 6, oc = idx & 63;
            int s = 0, n = 0;
            for (int tap = 0; tap < 9; ++tap) {
                int kh = tap / 3, kw = tap % 3;
                bool pad = ((pat & 1) && kh == 0) || ((pat & 2) && kh == 2) ||
                           ((pat & 4) && kw == 0) || ((pat & 8) && kw == 2);
                if (pad) { s += __popc(utab[TW_W2 + oc * 9 + tap]); ++n; }
            }
            tab[TW_CORR2 + idx] = 2 * s - 32 * n;
        }
        if (t < 256) {
            int pat = t >> 4, oc = t & 15;
            int s = 0, n = 0;
            for (int tap = 0; tap < 9; ++tap) {
                int kh = tap / 3, kw = tap % 3;
                bool pad = ((pat & 1) && kh == 0) || ((pat & 2) && kh == 2) ||
                           ((pat & 4) && kw == 0) || ((pat & 8) && kw == 2);
                if (pad) {
                    s += __popc(utab[TW_W3 + oc * 18 + tap * 2]) +
                         __popc(utab[TW_W3 + oc * 18 + tap * 2 + 1]);
                    ++n;
                }
            }
            tab[TW_CORR3 + t] = 2 * s - 64 * n;
        }
    } else if (blockIdx.x <= 52) {        // fc1_w [256][784] -> w1T [800][256]
        __shared__ float T[64][65];
        int bb = blockIdx.x - 1;          // 13 k-tiles x 4 n-tiles
        int kt = bb >> 2, nt = bb & 3;
#pragma unroll
        for (int s = 0; s < 16; ++s) {
            int idx = s * 256 + t;
            int nl = idx >> 6, kl = idx & 63;
            int k = kt * 64 + kl;
            T[nl][kl] = (k < 784) ? fc1_w[(nt * 64 + nl) * 784 + k] : 0.f;
        }
        __syncthreads();
#pragma unroll
        for (int s = 0; s < 16; ++s) {
            int idx = s * 256 + t;
            int kl = idx >> 6, nl = idx & 63;
            int k = kt * 64 + kl;
            if (k < 800) w1T[k * 256 + nt * 64 + nl] = T[nl][kl];
        }
    } else {                              // fc2_w [128][256] -> w2T [256][128]
        __shared__ float T[64][65];
        int bb = blockIdx.x - 53;         // 4 k-tiles x 2 n-tiles
        int kt = bb >> 1, nt = bb & 1;
#pragma unroll
        for (int s = 0; s < 16; ++s) {
            int idx = s * 256 + t;
            int nl = idx >> 6, kl = idx & 63;
            T[nl][kl] = fc2_w[(nt * 64 + nl) * 256 + kt * 64 + kl];
        }
        __syncthreads();
#pragma unroll
        for (int s = 0; s < 16; ++s) {
            int idx = s * 256 + t;
            int kl = idx >> 6, nl = idx & 63;
            w2T[(kt * 64 + kl) * 128 + nt * 64 + nl] = T[nl][kl];
        }
    }
}

// ---------------- conv stack: 4 images/block, 2 waves/image -----------------
// LDS (int32 words): [0..1023] corr2, [1024..1279] corr3,
//   per image i @ 1280+i*456: [0..29] xrow (zero pad rows 0/29),
//                             [32..287] H1 padded 16x16, [288..449] H2 9x9x2
#define WV 456

__global__ __launch_bounds__(512, 8) void conv_stack(
    const float* __restrict__ x,
    const float* __restrict__ b3,
    const int* __restrict__ tab,
    float* __restrict__ h3T) {            // [800][4096]
    __shared__ int SH[1280 + 4 * WV];
    const int t = threadIdx.x;
    const int wid = t >> 6, lane = t & 63;
    const int iml = wid >> 1, sw = wid & 1;   // image-local, sub-wave
    const int img = blockIdx.x * 4 + iml;
    const uint32_t* utab = (const uint32_t*)tab;
    uint32_t* W = (uint32_t*)&SH[1280 + iml * WV];

    // stage corr2+corr3 (contiguous 1280 words) and zero per-image regions
    for (int i = t; i < 1280; i += 512) SH[i] = tab[TW_CORR2 + i];
    for (int i = t; i < 4 * WV; i += 512) SH[1280 + i] = 0;
    __syncthreads();

    // load + binarize input rows: bit j+1 = (pixel j > 0); each wave 14 rows
    if (lane < 14) {
        int r = sw * 14 + lane;
        const float* xr = x + img * 784 + r * 28;
        uint32_t b = 0;
#pragma unroll
        for (int q = 0; q < 7; ++q) {
            float4 v = *(const float4*)(xr + q * 4);
            b |= (v.x > 0.f ? 1u : 0u) << (q * 4 + 0);
            b |= (v.y > 0.f ? 1u : 0u) << (q * 4 + 1);
            b |= (v.z > 0.f ? 1u : 0u) << (q * 4 + 2);
            b |= (v.w > 0.f ? 1u : 0u) << (q * 4 + 3);
        }
        W[1 + r] = b << 1;
    }
    __syncthreads();

    // ---- conv1 (1->32) + pool + binarize -> H1 ----
    auto conv1_int = [&](int p) {
        int Pi = 1 + p / 12, Pj = 1 + p % 12;
        int i0 = 2 * Pi, j0 = 2 * Pj;
        uint32_t r0 = W[i0], r1 = W[i0 + 1], r2 = W[i0 + 2], r3 = W[i0 + 3];
        uint32_t f0a = (r0 >> j0) & 7, f0b = (r0 >> (j0 + 1)) & 7;
        uint32_t f1a = (r1 >> j0) & 7, f1b = (r1 >> (j0 + 1)) & 7;
        uint32_t f2a = (r2 >> j0) & 7, f2b = (r2 >> (j0 + 1)) & 7;
        uint32_t f3a = (r3 >> j0) & 7, f3b = (r3 >> (j0 + 1)) & 7;
        uint32_t s00 = f0a | (f1a << 3) | (f2a << 6);
        uint32_t s01 = f0b | (f1b << 3) | (f2b << 6);
        uint32_t s10 = f1a | (f2a << 3) | (f3a << 6);
        uint32_t s11 = f1b | (f2b << 3) | (f3b << 6);
        uint32_t word = 0;
#pragma unroll
        for (int oc = 0; oc < 32; ++oc) {
            uint32_t w = utab[TW_WB1 + oc];
            int m0 = __popc(s00 ^ w), m1 = __popc(s01 ^ w);
            int m2 = __popc(s10 ^ w), m3 = __popc(s11 ^ w);
            int mn = imin2(imin2(m0, m1), imin2(m2, m3));
            word |= (mn <= tab[TW_TLE1 + oc] ? 1u : 0u) << oc;
        }
        W[32 + (Pi + 1) * 16 + (Pj + 1)] = word;
    };
    if (sw == 0) {
        conv1_int(lane);
        conv1_int(64 + lane);
    } else {
        if (lane < 16) conv1_int(128 + lane);
        // border pooled positions (52): masked taps
        int p = lane;
        bool act = p < 52;
        int pp = act ? p : 28;
        int Pi, Pj;
        if (pp < 14)      { Pi = 0;  Pj = pp; }
        else if (pp < 28) { Pi = 13; Pj = pp - 14; }
        else if (pp < 40) { Pi = pp - 28 + 1; Pj = 0; }
        else              { Pi = pp - 40 + 1; Pj = 13; }
        int i0 = 2 * Pi, j0 = 2 * Pj;
        uint32_t r0 = W[i0], r1 = W[i0 + 1], r2 = W[i0 + 2], r3 = W[i0 + 3];
        uint32_t f0a = (r0 >> j0) & 7, f0b = (r0 >> (j0 + 1)) & 7;
        uint32_t f1a = (r1 >> j0) & 7, f1b = (r1 >> (j0 + 1)) & 7;
        uint32_t f2a = (r2 >> j0) & 7, f2b = (r2 >> (j0 + 1)) & 7;
        uint32_t f3a = (r3 >> j0) & 7, f3b = (r3 >> (j0 + 1)) & 7;
        uint32_t smp[4];
        smp[0] = f0a | (f1a << 3) | (f2a << 6);
        smp[1] = f0b | (f1b << 3) | (f2b << 6);
        smp[2] = f1a | (f2a << 3) | (f3a << 6);
        smp[3] = f1b | (f2b << 3) | (f3b << 6);
        uint32_t mb[4];
        int pcm[4];
#pragma unroll
        for (int a = 0; a < 2; ++a) {
            int i = 2 * Pi + a;
            uint32_t vre = 0x1FF;
            if (i == 0)  vre &= ~0x007u;
            if (i == 27) vre &= ~0x1C0u;
#pragma unroll
            for (int bb = 0; bb < 2; ++bb) {
                int j = 2 * Pj + bb;
                uint32_t vce = 0x1FF;
                if (j == 0)  vce &= ~0x049u;
                if (j == 27) vce &= ~0x124u;
                mb[a * 2 + bb] = vre & vce;
                pcm[a * 2 + bb] = __popc(vre & vce);
            }
        }
        uint32_t word = 0;
#pragma unroll
        for (int oc = 0; oc < 32; ++oc) {
            uint32_t w = utab[TW_WB1 + oc];
            int best = -1000;
#pragma unroll
            for (int p4 = 0; p4 < 4; ++p4) {
                int v = pcm[p4] - 2 * __popc((smp[p4] ^ w) & mb[p4]);
                best = imax2(best, v);
            }
            word |= (best >= tab[TW_TGE1 + oc] ? 1u : 0u) << oc;
        }
        if (act) W[32 + (Pi + 1) * 16 + (Pj + 1)] = word;
    }
    __syncthreads();

    // ---- conv2 (32->64) + pool + binarize -> H2 via ballot ----
    {
        uint32_t w2r[9];
#pragma unroll
        for (int k = 0; k < 9; ++k) w2r[k] = utab[TW_W2 + lane * 9 + k];
        const int tle2 = tab[TW_TLE2 + lane];
        const int tge2 = tab[TW_TGE2 + lane];
        const uint32_t* H1 = W + 32;
        uint32_t* H2 = W + 288;

        // interior pooled Pi,Pj in 1..5 (25 positions): cheap min-path
        for (int q = sw; q < 25; q += 2) {
            int Pi = 1 + q / 5, Pj = 1 + q % 5;   // wave-uniform
            uint32_t c[16];
#pragma unroll
            for (int r = 0; r < 4; ++r) {
                uint2 lo = *(const uint2*)&H1[(2 * Pi + r) * 16 + 2 * Pj];
                uint2 hi = *(const uint2*)&H1[(2 * Pi + r) * 16 + 2 * Pj + 2];
                c[r * 4 + 0] = lo.x; c[r * 4 + 1] = lo.y;
                c[r * 4 + 2] = hi.x; c[r * 4 + 3] = hi.y;
            }
            int mn = 100000;
#pragma unroll
            for (int a = 0; a < 2; ++a)
#pragma unroll
                for (int bb = 0; bb < 2; ++bb) {
                    int s = 0;
#pragma unroll
                    for (int kh = 0; kh < 3; ++kh)
#pragma unroll
                        for (int kw = 0; kw < 3; ++kw)
                            s += __popc(c[(a + kh) * 4 + (bb + kw)] ^ w2r[kh * 3 + kw]);
                    mn = imin2(mn, s);
                }
            uint64_t bal = __ballot(mn <= tle2);
            if (lane == 0) {
                uint2 wv = make_uint2((uint32_t)bal, (uint32_t)(bal >> 32));
                *(uint2*)&H2[((Pi + 1) * 9 + (Pj + 1)) * 2] = wv;
            }
        }
        // border pooled (24): uniform popcount + pattern correction (LDS)
        for (int bp = sw; bp < 24; bp += 2) {
            int Pi, Pj;
            if (bp < 7)       { Pi = 0; Pj = bp; }
            else if (bp < 14) { Pi = 6; Pj = bp - 7; }
            else if (bp < 19) { Pi = bp - 14 + 1; Pj = 0; }
            else              { Pi = bp - 19 + 1; Pj = 6; }
            uint32_t c[16];
#pragma unroll
            for (int r = 0; r < 4; ++r) {
                uint2 lo = *(const uint2*)&H1[(2 * Pi + r) * 16 + 2 * Pj];
                uint2 hi = *(const uint2*)&H1[(2 * Pi + r) * 16 + 2 * Pj + 2];
                c[r * 4 + 0] = lo.x; c[r * 4 + 1] = lo.y;
                c[r * 4 + 2] = hi.x; c[r * 4 + 3] = hi.y;
            }
            int best = -100000;
#pragma unroll
            for (int a = 0; a < 2; ++a)
#pragma unroll
                for (int bb = 0; bb < 2; ++bb) {
                    int s = 0;
#pragma unroll
                    for (int kh = 0; kh < 3; ++kh)
#pragma unroll
                        for (int kw = 0; kw < 3; ++kw)
                            s += __popc(c[(a + kh) * 4 + (bb + kw)] ^ w2r[kh * 3 + kw]);
                    int i = 2 * Pi + a, j = 2 * Pj + bb;
                    int pat = (i == 0 ? 1 : 0) | (i == 13 ? 2 : 0) |
                              (j == 0 ? 4 : 0) | (j == 13 ? 8 : 0);
                    int D = 288 - 2 * s + SH[pat * 64 + lane];
                    best = imax2(best, D);
                }
            uint64_t bal = __ballot(best >= tge2);
            if (lane == 0) {
                uint2 wv = make_uint2((uint32_t)bal, (uint32_t)(bal >> 32));
                *(uint2*)&H2[((Pi + 1) * 9 + (Pj + 1)) * 2] = wv;
            }
        }
    }
    __syncthreads();

    // ---- conv3 (64->16) + bias + relu -> h3T[k][img] ----
    {
        const uint32_t* H2 = (const uint32_t*)W + 288;
        int oc = lane & 15, sub = lane >> 4;
        uint32_t w3r[18];
#pragma unroll
        for (int k = 0; k < 18; ++k) w3r[k] = utab[TW_W3 + oc * 18 + k];
        float bias3 = b3[oc];
        const int gbeg = sw ? 6 : 0, gend = sw ? 13 : 6;
        for (int g = gbeg; g < gend; ++g) {
            int pos = g * 4 + sub;
            bool act = pos < 49;
            int pp = act ? pos : 0;
            int Pi = pp / 7, Pj = pp % 7;
            int s = 0;
#pragma unroll
            for (int kh = 0; kh < 3; ++kh)
#pragma unroll
                for (int kw = 0; kw < 3; ++kw) {
                    uint2 hv = *(const uint2*)&H2[((Pi + kh) * 9 + (Pj + kw)) * 2];
                    s += __popc(hv.x ^ w3r[(kh * 3 + kw) * 2]) +
                         __popc(hv.y ^ w3r[(kh * 3 + kw) * 2 + 1]);
                }
            int pat = (Pi == 0 ? 1 : 0) | (Pi == 6 ? 2 : 0) |
                      (Pj == 0 ? 4 : 0) | (Pj == 6 ? 8 : 0);
            int D = 576 - 2 * s + SH[1024 + pat * 16 + oc];
            float h = (float)D + bias3;
            h = h > 0.f ? h : 0.f;
            if (act) h3T[(oc * 49 + pp) * 4096 + img] = h;
        }
    }
}

// ---------------- FC1: LDS-free, barrier-free, B in SGPRs -------------------
// Each wave owns 64 img x 16 n. A read coalesced from global (L2-resident:
// all 4 n-blocks of an img-tile land on the same XCD since 64 % 8 == 0).
// B rows are wave-uniform (readfirstlane'd wave id) -> scalar s_loads, FMA
// uses the SGPR operand slot. No LDS, no barriers, no staging.
__global__ __launch_bounds__(256) void fc1_gemm(
    const float* __restrict__ aT,    // h3T [800][4096]
    const float* __restrict__ bT,    // fc1_wT [800][256]
    const float* __restrict__ bias,
    float* __restrict__ oT) {        // h1T [256][4096]
    const int t = threadIdx.x;
    const int lane = t & 63;
    const int wu = __builtin_amdgcn_readfirstlane(t >> 6);   // 0..3, uniform
    const int img = blockIdx.x * 64 + lane;
    const int nw = blockIdx.y * 64 + wu * 16;
    const float* __restrict__ Ac = aT + img;
    const float* __restrict__ Bc = bT + nw;
    float acc[16];
#pragma unroll
    for (int j = 0; j < 16; ++j) acc[j] = 0.f;

#pragma unroll 8
    for (int k = 0; k < 800; ++k) {
        float a = Ac[k * 4096];
        const float4* B4 = (const float4*)(Bc + k * 256);
        float4 b0 = B4[0], b1 = B4[1], b2 = B4[2], b3 = B4[3];
        acc[0]  += a * b0.x; acc[1]  += a * b0.y;
        acc[2]  += a * b0.z; acc[3]  += a * b0.w;
        acc[4]  += a * b1.x; acc[5]  += a * b1.y;
        acc[6]  += a * b1.z; acc[7]  += a * b1.w;
        acc[8]  += a * b2.x; acc[9]  += a * b2.y;
        acc[10] += a * b2.z; acc[11] += a * b2.w;
        acc[12] += a * b3.x; acc[13] += a * b3.y;
        acc[14] += a * b3.z; acc[15] += a * b3.w;
    }
#pragma unroll
    for (int j = 0; j < 16; ++j) {
        float v = acc[j] + bias[nw + j];
        v = v > 0.f ? v : 0.f;
        oT[(nw + j) * 4096 + img] = v;
    }
}

// ---------------- FC2: same scheme, 64 img x 8 n per wave -------------------
__global__ __launch_bounds__(256) void fc2_gemm(
    const float* __restrict__ aT,    // h1T [256][4096]
    const float* __restrict__ bT,    // fc2_wT [256][128]
    const float* __restrict__ bias,
    float* __restrict__ oT) {        // h2T [128][4096]
    const int t = threadIdx.x;
    const int lane = t & 63;
    const int wu = __builtin_amdgcn_readfirstlane(t >> 6);   // 0..3
    const int img = blockIdx.x * 64 + lane;
    const int nw = blockIdx.y * 32 + wu * 8;
    const float* __restrict__ Ac = aT + img;
    const float* __restrict__ Bc = bT + nw;
    float acc[8];
#pragma unroll
    for (int j = 0; j < 8; ++j) acc[j] = 0.f;

#pragma unroll 8
    for (int k = 0; k < 256; ++k) {
        float a = Ac[k * 4096];
        const float4* B4 = (const float4*)(Bc + k * 128);
        float4 b0 = B4[0], b1 = B4[1];
        acc[0] += a * b0.x; acc[1] += a * b0.y;
        acc[2] += a * b0.z; acc[3] += a * b0.w;
        acc[4] += a * b1.x; acc[5] += a * b1.y;
        acc[6] += a * b1.z; acc[7] += a * b1.w;
    }
#pragma unroll
    for (int j = 0; j < 8; ++j) {
        float v = acc[j] + bias[nw + j];
        v = v > 0.f ? v : 0.f;
        oT[(nw + j) * 4096 + img] = v;
    }
}

// ---------------- FC3: [4096x128] x [128x10] -> out -------------------------
__global__ __launch_bounds__(256) void fc3_gemm(
    const float* __restrict__ aT,    // h2T [128][4096]
    const float* __restrict__ w,     // fc3_w [10][128]
    const float* __restrict__ bias,
    float* __restrict__ out) {       // [4096][10]
    int id = blockIdx.x * 256 + threadIdx.x;   // 40960
    int n = id >> 12, img = id & 4095;
    const float* wr = w + n * 128;
    float a0 = 0.f, a1 = 0.f, a2 = 0.f, a3 = 0.f;
#pragma unroll 8
    for (int k = 0; k < 128; k += 4) {
        a0 += aT[(k + 0) * 4096 + img] * wr[k + 0];
        a1 += aT[(k + 1) * 4096 + img] * wr[k + 1];
        a2 += aT[(k + 2) * 4096 + img] * wr[k + 2];
        a3 += aT[(k + 3) * 4096 + img] * wr[k + 3];
    }
    out[img * 10 + n] = (a0 + a1) + (a2 + a3) + bias[n];
}

extern "C" void kernel_launch(void* const* d_in, const int* in_sizes, int n_in,
                              void* d_out, int out_size, void* d_ws, size_t ws_size,
                              hipStream_t stream) {
    const float* x     = (const float*)d_in[0];
    const float* w1    = (const float*)d_in[1];
    const float* b1    = (const float*)d_in[2];
    const float* w2    = (const float*)d_in[3];
    const float* b2    = (const float*)d_in[4];
    const float* w3    = (const float*)d_in[5];
    const float* b3    = (const float*)d_in[6];
    const float* fc1_w = (const float*)d_in[7];
    const float* fc1_b = (const float*)d_in[8];
    const float* fc2_w = (const float*)d_in[9];
    const float* fc2_b = (const float*)d_in[10];
    const float* fc3_w = (const float*)d_in[11];
    const float* fc3_b = (const float*)d_in[12];
    float* out = (float*)d_out;

    const int B = in_sizes[0] / 784;  // 4096
    char* ws = (char*)d_ws;
    float* w1T = (float*)(ws + OFF_W1T);
    float* w2T = (float*)(ws + OFF_W2T);
    float* h3T = (float*)(ws + OFF_H3T);
    float* h1T = (float*)(ws + OFF_H1T);
    float* h2T = (float*)(ws + OFF_H2T);
    int* tab = (int*)(ws + OFF_H2T);  // tables alias h2T (disjoint lifetime)

    hipLaunchKernelGGL(prep, dim3(61), dim3(256), 0, stream,
                       w1, b1, w2, b2, w3, fc1_w, fc2_w, tab, w1T, w2T);
    hipLaunchKernelGGL(conv_stack, dim3(B / 4), dim3(512), 0, stream,
                       x, b3, tab, h3T);
    hipLaunchKernelGGL(fc1_gemm, dim3(B / 64, 4), dim3(256), 0, stream,
                       h3T, w1T, fc1_b, h1T);
    hipLaunchKernelGGL(fc2_gemm, dim3(B / 64, 4), dim3(256), 0, stream,
                       h1T, w2T, fc2_b, h2T);
    hipLaunchKernelGGL(fc3_gemm, dim3(B * 10 / 256), dim3(256), 0, stream,
                       h2T, fc3_w, fc3_b, out);
}

// Round 7
// 256.652 us; speedup vs baseline: 1.0903x; 1.0903x over previous
//
#include <hip/hip_runtime.h>
#include <cstdint>

// ---------------- ws layout (bytes) ----------------
// fc1_wT  @ 4096     : [800][256] f32 (zero-padded k>=784)   819200 B
// fc2_wT  @ 823296   : [256][128] f32                        131072 B
// h3T     @ 954368   : [800][4096] f32 (rows>=784 unused)  13107200 B
// h1      @ 14061568 : [4096][256] f32 (row-major img x n)   4194304 B
// h2      @ 18255872 : [4096][128] f32 (row-major img x n)   2097152 B
//   NOTE: conv tables live at OFF_H2 during {prep, conv_stack}; fc2 later
//   overwrites the region with h2. Lifetimes are disjoint (same stream).
#define OFF_W1T   4096
#define OFF_W2T   823296
#define OFF_H3T   954368
#define OFF_H1    14061568
#define OFF_H2    18255872

// table word offsets (int32 words, base = ws + OFF_H2)
#define TW_WB1    0      // [32]  conv1 weight bits (9 taps in bits 0..8)
#define TW_W2     32     // [576] conv2 bits: [oc64][tap9], 32 ic bits
#define TW_W3     608    // [288] conv3 bits: [oc16][tap9][word2], 32 ic bits
#define TW_CORR2  896    // [16][64] border correction, conv2
#define TW_CORR3  1920   // [16][16] border correction, conv3  (contig w/ CORR2)
#define TW_TLE1   2176   // [32] conv1 interior: bit <=> Smin <= tle1
#define TW_TGE1   2208   // [32] conv1 border:   bit <=> Dmax >= tge1
#define TW_TLE2   2240   // [64] conv2 interior: bit <=> Smin <= tle2
#define TW_TGE2   2304   // [64] conv2 border:   bit <=> Dmax >= tge2

__device__ __forceinline__ int imin2(int a, int b) { return a < b ? a : b; }
__device__ __forceinline__ int imax2(int a, int b) { return a > b ? a : b; }

// ---------------- prep ------------------------------------------------------
// block 0: tables. blocks 1..52: fc1_w transpose (64x64 LDS tiles, coalesced
// both sides). blocks 53..60: fc2_w transpose.
__global__ __launch_bounds__(256) void prep(
    const float* __restrict__ w1, const float* __restrict__ b1,
    const float* __restrict__ w2, const float* __restrict__ b2,
    const float* __restrict__ w3,
    const float* __restrict__ fc1_w, const float* __restrict__ fc2_w,
    int* __restrict__ tab, float* __restrict__ w1T, float* __restrict__ w2T) {
    int t = threadIdx.x;
    uint32_t* utab = (uint32_t*)tab;
    if (blockIdx.x == 0) {
        if (t < 32) {
            uint32_t b = 0;
            for (int k = 0; k < 9; ++k) b |= (w1[t * 9 + k] > 0.f ? 1u : 0u) << k;
            utab[TW_WB1 + t] = b;
            tab[TW_TLE1 + t] = (int)floorf((9.f + b1[t]) * 0.5f);
            tab[TW_TGE1 + t] = (int)floorf(-b1[t]) + 1;
        }
        if (t >= 32 && t < 96) {
            int oc = t - 32;
            tab[TW_TLE2 + oc] = (int)floorf((288.f + b2[oc]) * 0.5f);
            tab[TW_TGE2 + oc] = (int)floorf(-b2[oc]) + 1;
        }
        for (int idx = t; idx < 576; idx += 256) {
            int oc = idx / 9, tap = idx % 9;
            int kh = tap / 3, kw = tap % 3;
            uint32_t b = 0;
            for (int ic = 0; ic < 32; ++ic)
                b |= (w2[((oc * 32 + ic) * 3 + kh) * 3 + kw] > 0.f ? 1u : 0u) << ic;
            utab[TW_W2 + idx] = b;
        }
        for (int idx = t; idx < 288; idx += 256) {
            int oc = idx / 18, rem = idx % 18;
            int tap = rem >> 1, word = rem & 1;
            int kh = tap / 3, kw = tap % 3;
            uint32_t b = 0;
            for (int ic = 0; ic < 32; ++ic)
                b |= (w3[((oc * 64 + ic + 32 * word) * 3 + kh) * 3 + kw] > 0.f ? 1u : 0u) << ic;
            utab[TW_W3 + idx] = b;
        }
        __syncthreads();   // packed words -> visible for correction pass
        for (int idx = t; idx < 1024; idx += 256) {
            int pat = idx >> 6, oc = idx & 63;
            int s = 0, n = 0;
            for (int tap = 0; tap < 9; ++tap) {
                int kh = tap / 3, kw = tap % 3;
                bool pad = ((pat & 1) && kh == 0) || ((pat & 2) && kh == 2) ||
                           ((pat & 4) && kw == 0) || ((pat & 8) && kw == 2);
                if (pad) { s += __popc(utab[TW_W2 + oc * 9 + tap]); ++n; }
            }
            tab[TW_CORR2 + idx] = 2 * s - 32 * n;
        }
        if (t < 256) {
            int pat = t >> 4, oc = t & 15;
            int s = 0, n = 0;
            for (int tap = 0; tap < 9; ++tap) {
                int kh = tap / 3, kw = tap % 3;
                bool pad = ((pat & 1) && kh == 0) || ((pat & 2) && kh == 2) ||
                           ((pat & 4) && kw == 0) || ((pat & 8) && kw == 2);
                if (pad) {
                    s += __popc(utab[TW_W3 + oc * 18 + tap * 2]) +
                         __popc(utab[TW_W3 + oc * 18 + tap * 2 + 1]);
                    ++n;
                }
            }
            tab[TW_CORR3 + t] = 2 * s - 64 * n;
        }
    } else if (blockIdx.x <= 52) {        // fc1_w [256][784] -> w1T [800][256]
        __shared__ float T[64][65];
        int bb = blockIdx.x - 1;          // 13 k-tiles x 4 n-tiles
        int kt = bb >> 2, nt = bb & 3;
#pragma unroll
        for (int s = 0; s < 16; ++s) {
            int idx = s * 256 + t;
            int nl = idx >> 6, kl = idx & 63;
            int k = kt * 64 + kl;
            T[nl][kl] = (k < 784) ? fc1_w[(nt * 64 + nl) * 784 + k] : 0.f;
        }
        __syncthreads();
#pragma unroll
        for (int s = 0; s < 16; ++s) {
            int idx = s * 256 + t;
            int kl = idx >> 6, nl = idx & 63;
            int k = kt * 64 + kl;
            if (k < 800) w1T[k * 256 + nt * 64 + nl] = T[nl][kl];
        }
    } else {                              // fc2_w [128][256] -> w2T [256][128]
        __shared__ float T[64][65];
        int bb = blockIdx.x - 53;         // 4 k-tiles x 2 n-tiles
        int kt = bb >> 1, nt = bb & 1;
#pragma unroll
        for (int s = 0; s < 16; ++s) {
            int idx = s * 256 + t;
            int nl = idx >> 6, kl = idx & 63;
            T[nl][kl] = fc2_w[(nt * 64 + nl) * 256 + kt * 64 + kl];
        }
        __syncthreads();
#pragma unroll
        for (int s = 0; s < 16; ++s) {
            int idx = s * 256 + t;
            int kl = idx >> 6, nl = idx & 63;
            w2T[(kt * 64 + kl) * 128 + nt * 64 + nl] = T[nl][kl];
        }
    }
}

// ---------------- conv stack: 4 images/block, 2 waves/image -----------------
// LDS (int32 words): [0..1023] corr2, [1024..1279] corr3,
//   per image i @ 1280+i*456: [0..29] xrow (zero pad rows 0/29),
//                             [32..287] H1 padded 16x16, [288..449] H2 9x9x2
#define WV 456

__global__ __launch_bounds__(512, 8) void conv_stack(
    const float* __restrict__ x,
    const float* __restrict__ b3,
    const int* __restrict__ tab,
    float* __restrict__ h3T) {            // [800][4096]
    __shared__ int SH[1280 + 4 * WV];
    const int t = threadIdx.x;
    const int wid = t >> 6, lane = t & 63;
    const int iml = wid >> 1, sw = wid & 1;   // image-local, sub-wave
    const int img = blockIdx.x * 4 + iml;
    const uint32_t* utab = (const uint32_t*)tab;
    uint32_t* W = (uint32_t*)&SH[1280 + iml * WV];

    // stage corr2+corr3 (contiguous 1280 words) and zero per-image regions
    for (int i = t; i < 1280; i += 512) SH[i] = tab[TW_CORR2 + i];
    for (int i = t; i < 4 * WV; i += 512) SH[1280 + i] = 0;
    __syncthreads();

    // load + binarize input rows: bit j+1 = (pixel j > 0); each wave 14 rows
    if (lane < 14) {
        int r = sw * 14 + lane;
        const float* xr = x + img * 784 + r * 28;
        uint32_t b = 0;
#pragma unroll
        for (int q = 0; q < 7; ++q) {
            float4 v = *(const float4*)(xr + q * 4);
            b |= (v.x > 0.f ? 1u : 0u) << (q * 4 + 0);
            b |= (v.y > 0.f ? 1u : 0u) << (q * 4 + 1);
            b |= (v.z > 0.f ? 1u : 0u) << (q * 4 + 2);
            b |= (v.w > 0.f ? 1u : 0u) << (q * 4 + 3);
        }
        W[1 + r] = b << 1;
    }
    __syncthreads();

    // ---- conv1 (1->32) + pool + binarize -> H1 ----
    auto conv1_int = [&](int p) {
        int Pi = 1 + p / 12, Pj = 1 + p % 12;
        int i0 = 2 * Pi, j0 = 2 * Pj;
        uint32_t r0 = W[i0], r1 = W[i0 + 1], r2 = W[i0 + 2], r3 = W[i0 + 3];
        uint32_t f0a = (r0 >> j0) & 7, f0b = (r0 >> (j0 + 1)) & 7;
        uint32_t f1a = (r1 >> j0) & 7, f1b = (r1 >> (j0 + 1)) & 7;
        uint32_t f2a = (r2 >> j0) & 7, f2b = (r2 >> (j0 + 1)) & 7;
        uint32_t f3a = (r3 >> j0) & 7, f3b = (r3 >> (j0 + 1)) & 7;
        uint32_t s00 = f0a | (f1a << 3) | (f2a << 6);
        uint32_t s01 = f0b | (f1b << 3) | (f2b << 6);
        uint32_t s10 = f1a | (f2a << 3) | (f3a << 6);
        uint32_t s11 = f1b | (f2b << 3) | (f3b << 6);
        uint32_t word = 0;
#pragma unroll
        for (int oc = 0; oc < 32; ++oc) {
            uint32_t w = utab[TW_WB1 + oc];
            int m0 = __popc(s00 ^ w), m1 = __popc(s01 ^ w);
            int m2 = __popc(s10 ^ w), m3 = __popc(s11 ^ w);
            int mn = imin2(imin2(m0, m1), imin2(m2, m3));
            word |= (mn <= tab[TW_TLE1 + oc] ? 1u : 0u) << oc;
        }
        W[32 + (Pi + 1) * 16 + (Pj + 1)] = word;
    };
    if (sw == 0) {
        conv1_int(lane);
        conv1_int(64 + lane);
    } else {
        if (lane < 16) conv1_int(128 + lane);
        // border pooled positions (52): masked taps
        int p = lane;
        bool act = p < 52;
        int pp = act ? p : 28;
        int Pi, Pj;
        if (pp < 14)      { Pi = 0;  Pj = pp; }
        else if (pp < 28) { Pi = 13; Pj = pp - 14; }
        else if (pp < 40) { Pi = pp - 28 + 1; Pj = 0; }
        else              { Pi = pp - 40 + 1; Pj = 13; }
        int i0 = 2 * Pi, j0 = 2 * Pj;
        uint32_t r0 = W[i0], r1 = W[i0 + 1], r2 = W[i0 + 2], r3 = W[i0 + 3];
        uint32_t f0a = (r0 >> j0) & 7, f0b = (r0 >> (j0 + 1)) & 7;
        uint32_t f1a = (r1 >> j0) & 7, f1b = (r1 >> (j0 + 1)) & 7;
        uint32_t f2a = (r2 >> j0) & 7, f2b = (r2 >> (j0 + 1)) & 7;
        uint32_t f3a = (r3 >> j0) & 7, f3b = (r3 >> (j0 + 1)) & 7;
        uint32_t smp[4];
        smp[0] = f0a | (f1a << 3) | (f2a << 6);
        smp[1] = f0b | (f1b << 3) | (f2b << 6);
        smp[2] = f1a | (f2a << 3) | (f3a << 6);
        smp[3] = f1b | (f2b << 3) | (f3b << 6);
        uint32_t mb[4];
        int pcm[4];
#pragma unroll
        for (int a = 0; a < 2; ++a) {
            int i = 2 * Pi + a;
            uint32_t vre = 0x1FF;
            if (i == 0)  vre &= ~0x007u;
            if (i == 27) vre &= ~0x1C0u;
#pragma unroll
            for (int bb = 0; bb < 2; ++bb) {
                int j = 2 * Pj + bb;
                uint32_t vce = 0x1FF;
                if (j == 0)  vce &= ~0x049u;
                if (j == 27) vce &= ~0x124u;
                mb[a * 2 + bb] = vre & vce;
                pcm[a * 2 + bb] = __popc(vre & vce);
            }
        }
        uint32_t word = 0;
#pragma unroll
        for (int oc = 0; oc < 32; ++oc) {
            uint32_t w = utab[TW_WB1 + oc];
            int best = -1000;
#pragma unroll
            for (int p4 = 0; p4 < 4; ++p4) {
                int v = pcm[p4] - 2 * __popc((smp[p4] ^ w) & mb[p4]);
                best = imax2(best, v);
            }
            word |= (best >= tab[TW_TGE1 + oc] ? 1u : 0u) << oc;
        }
        if (act) W[32 + (Pi + 1) * 16 + (Pj + 1)] = word;
    }
    __syncthreads();

    // ---- conv2 (32->64) + pool + binarize -> H2 via ballot ----
    {
        uint32_t w2r[9];
#pragma unroll
        for (int k = 0; k < 9; ++k) w2r[k] = utab[TW_W2 + lane * 9 + k];
        const int tle2 = tab[TW_TLE2 + lane];
        const int tge2 = tab[TW_TGE2 + lane];
        const uint32_t* H1 = W + 32;
        uint32_t* H2 = W + 288;

        // interior pooled Pi,Pj in 1..5 (25 positions): cheap min-path
        for (int q = sw; q < 25; q += 2) {
            int Pi = 1 + q / 5, Pj = 1 + q % 5;   // wave-uniform
            uint32_t c[16];
#pragma unroll
            for (int r = 0; r < 4; ++r) {
                uint2 lo = *(const uint2*)&H1[(2 * Pi + r) * 16 + 2 * Pj];
                uint2 hi = *(const uint2*)&H1[(2 * Pi + r) * 16 + 2 * Pj + 2];
                c[r * 4 + 0] = lo.x; c[r * 4 + 1] = lo.y;
                c[r * 4 + 2] = hi.x; c[r * 4 + 3] = hi.y;
            }
            int mn = 100000;
#pragma unroll
            for (int a = 0; a < 2; ++a)
#pragma unroll
                for (int bb = 0; bb < 2; ++bb) {
                    int s = 0;
#pragma unroll
                    for (int kh = 0; kh < 3; ++kh)
#pragma unroll
                        for (int kw = 0; kw < 3; ++kw)
                            s += __popc(c[(a + kh) * 4 + (bb + kw)] ^ w2r[kh * 3 + kw]);
                    mn = imin2(mn, s);
                }
            uint64_t bal = __ballot(mn <= tle2);
            if (lane == 0) {
                uint2 wv = make_uint2((uint32_t)bal, (uint32_t)(bal >> 32));
                *(uint2*)&H2[((Pi + 1) * 9 + (Pj + 1)) * 2] = wv;
            }
        }
        // border pooled (24): uniform popcount + pattern correction (LDS)
        for (int bp = sw; bp < 24; bp += 2) {
            int Pi, Pj;
            if (bp < 7)       { Pi = 0; Pj = bp; }
            else if (bp < 14) { Pi = 6; Pj = bp - 7; }
            else if (bp < 19) { Pi = bp - 14 + 1; Pj = 0; }
            else              { Pi = bp - 19 + 1; Pj = 6; }
            uint32_t c[16];
#pragma unroll
            for (int r = 0; r < 4; ++r) {
                uint2 lo = *(const uint2*)&H1[(2 * Pi + r) * 16 + 2 * Pj];
                uint2 hi = *(const uint2*)&H1[(2 * Pi + r) * 16 + 2 * Pj + 2];
                c[r * 4 + 0] = lo.x; c[r * 4 + 1] = lo.y;
                c[r * 4 + 2] = hi.x; c[r * 4 + 3] = hi.y;
            }
            int best = -100000;
#pragma unroll
            for (int a = 0; a < 2; ++a)
#pragma unroll
                for (int bb = 0; bb < 2; ++bb) {
                    int s = 0;
#pragma unroll
                    for (int kh = 0; kh < 3; ++kh)
#pragma unroll
                        for (int kw = 0; kw < 3; ++kw)
                            s += __popc(c[(a + kh) * 4 + (bb + kw)] ^ w2r[kh * 3 + kw]);
                    int i = 2 * Pi + a, j = 2 * Pj + bb;
                    int pat = (i == 0 ? 1 : 0) | (i == 13 ? 2 : 0) |
                              (j == 0 ? 4 : 0) | (j == 13 ? 8 : 0);
                    int D = 288 - 2 * s + SH[pat * 64 + lane];
                    best = imax2(best, D);
                }
            uint64_t bal = __ballot(best >= tge2);
            if (lane == 0) {
                uint2 wv = make_uint2((uint32_t)bal, (uint32_t)(bal >> 32));
                *(uint2*)&H2[((Pi + 1) * 9 + (Pj + 1)) * 2] = wv;
            }
        }
    }
    __syncthreads();

    // ---- conv3 (64->16) + bias + relu -> h3T[k][img] ----
    {
        const uint32_t* H2 = (const uint32_t*)W + 288;
        int oc = lane & 15, sub = lane >> 4;
        uint32_t w3r[18];
#pragma unroll
        for (int k = 0; k < 18; ++k) w3r[k] = utab[TW_W3 + oc * 18 + k];
        float bias3 = b3[oc];
        const int gbeg = sw ? 6 : 0, gend = sw ? 13 : 6;
        for (int g = gbeg; g < gend; ++g) {
            int pos = g * 4 + sub;
            bool act = pos < 49;
            int pp = act ? pos : 0;
            int Pi = pp / 7, Pj = pp % 7;
            int s = 0;
#pragma unroll
            for (int kh = 0; kh < 3; ++kh)
#pragma unroll
                for (int kw = 0; kw < 3; ++kw) {
                    uint2 hv = *(const uint2*)&H2[((Pi + kh) * 9 + (Pj + kw)) * 2];
                    s += __popc(hv.x ^ w3r[(kh * 3 + kw) * 2]) +
                         __popc(hv.y ^ w3r[(kh * 3 + kw) * 2 + 1]);
                }
            int pat = (Pi == 0 ? 1 : 0) | (Pi == 6 ? 2 : 0) |
                      (Pj == 0 ? 4 : 0) | (Pj == 6 ? 8 : 0);
            int D = 576 - 2 * s + SH[1024 + pat * 16 + oc];
            float h = (float)D + bias3;
            h = h > 0.f ? h : 0.f;
            if (act) h3T[(oc * 49 + pp) * 4096 + img] = h;
        }
    }
}

// ---------------- FC1: lane = n; A rows via scalar loads --------------------
// Block = 256 thr (4 waves x 64 n = 256 n), 8 images/block. Per k:
//   B row w1T[k][n]   -> per-lane coalesced dword load (VMEM)
//   A    h3T[k][i0+i] -> 8 contiguous floats, wave-uniform -> scalar loads
//   8x v_fmac(v, s, v).  No LDS, no barriers.
// grid 512 = 2 blocks/CU -> 2 waves/SIMD; B L2 traffic 512x800KB=410MB ~12us.
__global__ __launch_bounds__(256) void fc1_gemm(
    const float* __restrict__ aT,    // h3T [800][4096]
    const float* __restrict__ bT,    // w1T [800][256]
    const float* __restrict__ bias,
    float* __restrict__ o) {         // h1 [4096][256]
    const int t = threadIdx.x;
    const int lane = t & 63, wq = t >> 6;
    const int img0 = blockIdx.x * 8;
    const int n = wq * 64 + lane;
    const float* __restrict__ Ap = aT + img0;
    const float* __restrict__ Bp = bT + n;
    float acc[8];
#pragma unroll
    for (int i = 0; i < 8; ++i) acc[i] = 0.f;

#pragma unroll 8
    for (int k = 0; k < 800; ++k) {
        float b = Bp[k * 256];
        const float* __restrict__ ar = Ap + k * 4096;   // uniform address
#pragma unroll
        for (int i = 0; i < 8; ++i) acc[i] += ar[i] * b;
    }
    float bs = bias[n];
#pragma unroll
    for (int i = 0; i < 8; ++i)
        o[(img0 + i) * 256 + n] = fmaxf(acc[i] + bs, 0.f);
}

// ---------------- FC2: same scheme; lane covers 2 n, 2 img/wave -------------
__global__ __launch_bounds__(256) void fc2_gemm(
    const float* __restrict__ a,     // h1 [4096][256]
    const float* __restrict__ bT,    // w2T [256][128]
    const float* __restrict__ bias,
    float* __restrict__ o) {         // h2 [4096][128]
    const int t = threadIdx.x;
    const int lane = t & 63, w = t >> 6;
    const int img0 = blockIdx.x * 8 + w * 2;
    const float* __restrict__ A0 = a + img0 * 256;      // uniform, contig in k
    const float* __restrict__ A1 = A0 + 256;
    float acc00 = 0.f, acc01 = 0.f, acc10 = 0.f, acc11 = 0.f;

#pragma unroll 8
    for (int k = 0; k < 256; ++k) {
        float b0 = bT[k * 128 + lane];
        float b1 = bT[k * 128 + 64 + lane];
        float a0 = A0[k], a1 = A1[k];                   // scalar loads
        acc00 += a0 * b0; acc01 += a0 * b1;
        acc10 += a1 * b0; acc11 += a1 * b1;
    }
    float bs0 = bias[lane], bs1 = bias[64 + lane];
    o[img0 * 128 + lane]            = fmaxf(acc00 + bs0, 0.f);
    o[img0 * 128 + 64 + lane]       = fmaxf(acc01 + bs1, 0.f);
    o[(img0 + 1) * 128 + lane]      = fmaxf(acc10 + bs0, 0.f);
    o[(img0 + 1) * 128 + 64 + lane] = fmaxf(acc11 + bs1, 0.f);
}

// ---------------- FC3: [4096x128] x [128x10] -> out -------------------------
// h2 row-major: per-thread float4 row reads; w row wave-uniform.
__global__ __launch_bounds__(256) void fc3_gemm(
    const float* __restrict__ a,     // h2 [4096][128]
    const float* __restrict__ w,     // fc3_w [10][128]
    const float* __restrict__ bias,
    float* __restrict__ out) {       // [4096][10]
    int id = blockIdx.x * 256 + threadIdx.x;   // 40960
    int n = id >> 12, img = id & 4095;
    const float* __restrict__ wr = w + n * 128;   // wave-uniform
    const float* __restrict__ ar = a + img * 128;
    float a0 = 0.f, a1 = 0.f, a2 = 0.f, a3 = 0.f;
#pragma unroll 8
    for (int k = 0; k < 128; k += 4) {
        float4 v = *(const float4*)&ar[k];
        a0 += v.x * wr[k + 0];
        a1 += v.y * wr[k + 1];
        a2 += v.z * wr[k + 2];
        a3 += v.w * wr[k + 3];
    }
    out[img * 10 + n] = (a0 + a1) + (a2 + a3) + bias[n];
}

extern "C" void kernel_launch(void* const* d_in, const int* in_sizes, int n_in,
                              void* d_out, int out_size, void* d_ws, size_t ws_size,
                              hipStream_t stream) {
    const float* x     = (const float*)d_in[0];
    const float* w1    = (const float*)d_in[1];
    const float* b1    = (const float*)d_in[2];
    const float* w2    = (const float*)d_in[3];
    const float* b2    = (const float*)d_in[4];
    const float* w3    = (const float*)d_in[5];
    const float* b3    = (const float*)d_in[6];
    const float* fc1_w = (const float*)d_in[7];
    const float* fc1_b = (const float*)d_in[8];
    const float* fc2_w = (const float*)d_in[9];
    const float* fc2_b = (const float*)d_in[10];
    const float* fc3_w = (const float*)d_in[11];
    const float* fc3_b = (const float*)d_in[12];
    float* out = (float*)d_out;

    const int B = in_sizes[0] / 784;  // 4096
    char* ws = (char*)d_ws;
    float* w1T = (float*)(ws + OFF_W1T);
    float* w2T = (float*)(ws + OFF_W2T);
    float* h3T = (float*)(ws + OFF_H3T);
    float* h1  = (float*)(ws + OFF_H1);
    float* h2  = (float*)(ws + OFF_H2);
    int* tab = (int*)(ws + OFF_H2);   // tables alias h2 (disjoint lifetime)

    hipLaunchKernelGGL(prep, dim3(61), dim3(256), 0, stream,
                       w1, b1, w2, b2, w3, fc1_w, fc2_w, tab, w1T, w2T);
    hipLaunchKernelGGL(conv_stack, dim3(B / 4), dim3(512), 0, stream,
                       x, b3, tab, h3T);
    hipLaunchKernelGGL(fc1_gemm, dim3(B / 8), dim3(256), 0, stream,
                       h3T, w1T, fc1_b, h1);
    hipLaunchKernelGGL(fc2_gemm, dim3(B / 8), dim3(256), 0, stream,
                       h1, w2T, fc2_b, h2);
    hipLaunchKernelGGL(fc3_gemm, dim3(B * 10 / 256), dim3(256), 0, stream,
                       h2, fc3_w, fc3_b, out);
}

// Round 8
// 215.421 us; speedup vs baseline: 1.2990x; 1.1914x over previous
//
#include <hip/hip_runtime.h>
#include <cstdint>

// ---------------- ws layout (bytes) ----------------
// fc1_wT  @ 4096     : [800][256] f32 (zero-padded k>=784)   819200 B
// fc2_wT  @ 823296   : [256][128] f32                        131072 B
// h3T     @ 954368   : [800][4096] f32 (rows>=784 unused)  13107200 B
// h1T     @ 14061568 : [256][4096] f32                      4194304 B
// h2T     @ 18255872 : [128][4096] f32                      2097152 B
//   NOTE: conv tables live at OFF_H2T during {prep, conv_stack}; fc2 later
//   overwrites the region with h2T. Lifetimes are disjoint (same stream).
#define OFF_W1T   4096
#define OFF_W2T   823296
#define OFF_H3T   954368
#define OFF_H1T   14061568
#define OFF_H2T   18255872

// table word offsets (int32 words, base = ws + OFF_H2T)
#define TW_WB1    0      // [32]  conv1 weight bits (9 taps in bits 0..8)
#define TW_W2     32     // [576] conv2 bits: [oc64][tap9], 32 ic bits
#define TW_W3     608    // [288] conv3 bits: [oc16][tap9][word2], 32 ic bits
#define TW_CORR2  896    // [16][64] border correction, conv2
#define TW_CORR3  1920   // [16][16] border correction, conv3  (contig w/ CORR2)
#define TW_TLE1   2176   // [32] conv1 interior: bit <=> Smin <= tle1
#define TW_TGE1   2208   // [32] conv1 border:   bit <=> Dmax >= tge1
#define TW_TLE2   2240   // [64] conv2 interior: bit <=> Smin <= tle2
#define TW_TGE2   2304   // [64] conv2 border:   bit <=> Dmax >= tge2

__device__ __forceinline__ int imin2(int a, int b) { return a < b ? a : b; }
__device__ __forceinline__ int imax2(int a, int b) { return a > b ? a : b; }

// async global->LDS 16B: lds dest = wave-uniform base + lane*16 (HW rule)
__device__ __forceinline__ void gload16(const float* g, float* lbase, int lane) {
#if __has_builtin(__builtin_amdgcn_global_load_lds)
    __builtin_amdgcn_global_load_lds(
        (const __attribute__((address_space(1))) uint32_t*)g,
        (__attribute__((address_space(3))) uint32_t*)lbase, 16, 0, 0);
#else
    *(float4*)&lbase[lane * 4] = *(const float4*)g;
#endif
}

// ---------------- prep ------------------------------------------------------
// block 0: tables. blocks 1..52: fc1_w transpose (64x64 LDS tiles, coalesced
// both sides). blocks 53..60: fc2_w transpose.
__global__ __launch_bounds__(256) void prep(
    const float* __restrict__ w1, const float* __restrict__ b1,
    const float* __restrict__ w2, const float* __restrict__ b2,
    const float* __restrict__ w3,
    const float* __restrict__ fc1_w, const float* __restrict__ fc2_w,
    int* __restrict__ tab, float* __restrict__ w1T, float* __restrict__ w2T) {
    int t = threadIdx.x;
    uint32_t* utab = (uint32_t*)tab;
    if (blockIdx.x == 0) {
        if (t < 32) {
            uint32_t b = 0;
            for (int k = 0; k < 9; ++k) b |= (w1[t * 9 + k] > 0.f ? 1u : 0u) << k;
            utab[TW_WB1 + t] = b;
            tab[TW_TLE1 + t] = (int)floorf((9.f + b1[t]) * 0.5f);
            tab[TW_TGE1 + t] = (int)floorf(-b1[t]) + 1;
        }
        if (t >= 32 && t < 96) {
            int oc = t - 32;
            tab[TW_TLE2 + oc] = (int)floorf((288.f + b2[oc]) * 0.5f);
            tab[TW_TGE2 + oc] = (int)floorf(-b2[oc]) + 1;
        }
        for (int idx = t; idx < 576; idx += 256) {
            int oc = idx / 9, tap = idx % 9;
            int kh = tap / 3, kw = tap % 3;
            uint32_t b = 0;
            for (int ic = 0; ic < 32; ++ic)
                b |= (w2[((oc * 32 + ic) * 3 + kh) * 3 + kw] > 0.f ? 1u : 0u) << ic;
            utab[TW_W2 + idx] = b;
        }
        for (int idx = t; idx < 288; idx += 256) {
            int oc = idx / 18, rem = idx % 18;
            int tap = rem >> 1, word = rem & 1;
            int kh = tap / 3, kw = tap % 3;
            uint32_t b = 0;
            for (int ic = 0; ic < 32; ++ic)
                b |= (w3[((oc * 64 + ic + 32 * word) * 3 + kh) * 3 + kw] > 0.f ? 1u : 0u) << ic;
            utab[TW_W3 + idx] = b;
        }
        __syncthreads();   // packed words -> visible for correction pass
        for (int idx = t; idx < 1024; idx += 256) {
            int pat = idx >> 6, oc = idx & 63;
            int s = 0, n = 0;
            for (int tap = 0; tap < 9; ++tap) {
                int kh = tap / 3, kw = tap % 3;
                bool pad = ((pat & 1) && kh == 0) || ((pat & 2) && kh == 2) ||
                           ((pat & 4) && kw == 0) || ((pat & 8) && kw == 2);
                if (pad) { s += __popc(utab[TW_W2 + oc * 9 + tap]); ++n; }
            }
            tab[TW_CORR2 + idx] = 2 * s - 32 * n;
        }
        if (t < 256) {
            int pat = t >> 4, oc = t & 15;
            int s = 0, n = 0;
            for (int tap = 0; tap < 9; ++tap) {
                int kh = tap / 3, kw = tap % 3;
                bool pad = ((pat & 1) && kh == 0) || ((pat & 2) && kh == 2) ||
                           ((pat & 4) && kw == 0) || ((pat & 8) && kw == 2);
                if (pad) {
                    s += __popc(utab[TW_W3 + oc * 18 + tap * 2]) +
                         __popc(utab[TW_W3 + oc * 18 + tap * 2 + 1]);
                    ++n;
                }
            }
            tab[TW_CORR3 + t] = 2 * s - 64 * n;
        }
    } else if (blockIdx.x <= 52) {        // fc1_w [256][784] -> w1T [800][256]
        __shared__ float T[64][65];
        int bb = blockIdx.x - 1;          // 13 k-tiles x 4 n-tiles
        int kt = bb >> 2, nt = bb & 3;
#pragma unroll
        for (int s = 0; s < 16; ++s) {
            int idx = s * 256 + t;
            int nl = idx >> 6, kl = idx & 63;
            int k = kt * 64 + kl;
            T[nl][kl] = (k < 784) ? fc1_w[(nt * 64 + nl) * 784 + k] : 0.f;
        }
        __syncthreads();
#pragma unroll
        for (int s = 0; s < 16; ++s) {
            int idx = s * 256 + t;
            int kl = idx >> 6, nl = idx & 63;
            int k = kt * 64 + kl;
            if (k < 800) w1T[k * 256 + nt * 64 + nl] = T[nl][kl];
        }
    } else {                              // fc2_w [128][256] -> w2T [256][128]
        __shared__ float T[64][65];
        int bb = blockIdx.x - 53;         // 4 k-tiles x 2 n-tiles
        int kt = bb >> 1, nt = bb & 1;
#pragma unroll
        for (int s = 0; s < 16; ++s) {
            int idx = s * 256 + t;
            int nl = idx >> 6, kl = idx & 63;
            T[nl][kl] = fc2_w[(nt * 64 + nl) * 256 + kt * 64 + kl];
        }
        __syncthreads();
#pragma unroll
        for (int s = 0; s < 16; ++s) {
            int idx = s * 256 + t;
            int kl = idx >> 6, nl = idx & 63;
            w2T[(kt * 64 + kl) * 128 + nt * 64 + nl] = T[nl][kl];
        }
    }
}

// ---------------- conv stack: 4 images/block, 2 waves/image -----------------
// LDS (int32 words): [0..1023] corr2, [1024..1279] corr3,
//   per image i @ 1280+i*456: [0..29] xrow (zero pad rows 0/29),
//                             [32..287] H1 padded 16x16, [288..449] H2 9x9x2
#define WV 456

__global__ __launch_bounds__(512, 8) void conv_stack(
    const float* __restrict__ x,
    const float* __restrict__ b3,
    const int* __restrict__ tab,
    float* __restrict__ h3T) {            // [800][4096]
    __shared__ int SH[1280 + 4 * WV];
    const int t = threadIdx.x;
    const int wid = t >> 6, lane = t & 63;
    const int iml = wid >> 1, sw = wid & 1;   // image-local, sub-wave
    const int img = blockIdx.x * 4 + iml;
    const uint32_t* utab = (const uint32_t*)tab;
    uint32_t* W = (uint32_t*)&SH[1280 + iml * WV];

    // stage corr2+corr3 (contiguous 1280 words) and zero per-image regions
    for (int i = t; i < 1280; i += 512) SH[i] = tab[TW_CORR2 + i];
    for (int i = t; i < 4 * WV; i += 512) SH[1280 + i] = 0;
    __syncthreads();

    // load + binarize input rows: bit j+1 = (pixel j > 0); each wave 14 rows
    if (lane < 14) {
        int r = sw * 14 + lane;
        const float* xr = x + img * 784 + r * 28;
        uint32_t b = 0;
#pragma unroll
        for (int q = 0; q < 7; ++q) {
            float4 v = *(const float4*)(xr + q * 4);
            b |= (v.x > 0.f ? 1u : 0u) << (q * 4 + 0);
            b |= (v.y > 0.f ? 1u : 0u) << (q * 4 + 1);
            b |= (v.z > 0.f ? 1u : 0u) << (q * 4 + 2);
            b |= (v.w > 0.f ? 1u : 0u) << (q * 4 + 3);
        }
        W[1 + r] = b << 1;
    }
    __syncthreads();

    // ---- conv1 (1->32) + pool + binarize -> H1 ----
    auto conv1_int = [&](int p) {
        int Pi = 1 + p / 12, Pj = 1 + p % 12;
        int i0 = 2 * Pi, j0 = 2 * Pj;
        uint32_t r0 = W[i0], r1 = W[i0 + 1], r2 = W[i0 + 2], r3 = W[i0 + 3];
        uint32_t f0a = (r0 >> j0) & 7, f0b = (r0 >> (j0 + 1)) & 7;
        uint32_t f1a = (r1 >> j0) & 7, f1b = (r1 >> (j0 + 1)) & 7;
        uint32_t f2a = (r2 >> j0) & 7, f2b = (r2 >> (j0 + 1)) & 7;
        uint32_t f3a = (r3 >> j0) & 7, f3b = (r3 >> (j0 + 1)) & 7;
        uint32_t s00 = f0a | (f1a << 3) | (f2a << 6);
        uint32_t s01 = f0b | (f1b << 3) | (f2b << 6);
        uint32_t s10 = f1a | (f2a << 3) | (f3a << 6);
        uint32_t s11 = f1b | (f2b << 3) | (f3b << 6);
        uint32_t word = 0;
#pragma unroll
        for (int oc = 0; oc < 32; ++oc) {
            uint32_t w = utab[TW_WB1 + oc];
            int m0 = __popc(s00 ^ w), m1 = __popc(s01 ^ w);
            int m2 = __popc(s10 ^ w), m3 = __popc(s11 ^ w);
            int mn = imin2(imin2(m0, m1), imin2(m2, m3));
            word |= (mn <= tab[TW_TLE1 + oc] ? 1u : 0u) << oc;
        }
        W[32 + (Pi + 1) * 16 + (Pj + 1)] = word;
    };
    if (sw == 0) {
        conv1_int(lane);
        conv1_int(64 + lane);
    } else {
        if (lane < 16) conv1_int(128 + lane);
        // border pooled positions (52): masked taps
        int p = lane;
        bool act = p < 52;
        int pp = act ? p : 28;
        int Pi, Pj;
        if (pp < 14)      { Pi = 0;  Pj = pp; }
        else if (pp < 28) { Pi = 13; Pj = pp - 14; }
        else if (pp < 40) { Pi = pp - 28 + 1; Pj = 0; }
        else              { Pi = pp - 40 + 1; Pj = 13; }
        int i0 = 2 * Pi, j0 = 2 * Pj;
        uint32_t r0 = W[i0], r1 = W[i0 + 1], r2 = W[i0 + 2], r3 = W[i0 + 3];
        uint32_t f0a = (r0 >> j0) & 7, f0b = (r0 >> (j0 + 1)) & 7;
        uint32_t f1a = (r1 >> j0) & 7, f1b = (r1 >> (j0 + 1)) & 7;
        uint32_t f2a = (r2 >> j0) & 7, f2b = (r2 >> (j0 + 1)) & 7;
        uint32_t f3a = (r3 >> j0) & 7, f3b = (r3 >> (j0 + 1)) & 7;
        uint32_t smp[4];
        smp[0] = f0a | (f1a << 3) | (f2a << 6);
        smp[1] = f0b | (f1b << 3) | (f2b << 6);
        smp[2] = f1a | (f2a << 3) | (f3a << 6);
        smp[3] = f1b | (f2b << 3) | (f3b << 6);
        uint32_t mb[4];
        int pcm[4];
#pragma unroll
        for (int a = 0; a < 2; ++a) {
            int i = 2 * Pi + a;
            uint32_t vre = 0x1FF;
            if (i == 0)  vre &= ~0x007u;
            if (i == 27) vre &= ~0x1C0u;
#pragma unroll
            for (int bb = 0; bb < 2; ++bb) {
                int j = 2 * Pj + bb;
                uint32_t vce = 0x1FF;
                if (j == 0)  vce &= ~0x049u;
                if (j == 27) vce &= ~0x124u;
                mb[a * 2 + bb] = vre & vce;
                pcm[a * 2 + bb] = __popc(vre & vce);
            }
        }
        uint32_t word = 0;
#pragma unroll
        for (int oc = 0; oc < 32; ++oc) {
            uint32_t w = utab[TW_WB1 + oc];
            int best = -1000;
#pragma unroll
            for (int p4 = 0; p4 < 4; ++p4) {
                int v = pcm[p4] - 2 * __popc((smp[p4] ^ w) & mb[p4]);
                best = imax2(best, v);
            }
            word |= (best >= tab[TW_TGE1 + oc] ? 1u : 0u) << oc;
        }
        if (act) W[32 + (Pi + 1) * 16 + (Pj + 1)] = word;
    }
    __syncthreads();

    // ---- conv2 (32->64) + pool + binarize -> H2 via ballot ----
    {
        uint32_t w2r[9];
#pragma unroll
        for (int k = 0; k < 9; ++k) w2r[k] = utab[TW_W2 + lane * 9 + k];
        const int tle2 = tab[TW_TLE2 + lane];
        const int tge2 = tab[TW_TGE2 + lane];
        const uint32_t* H1 = W + 32;
        uint32_t* H2 = W + 288;

        // interior pooled Pi,Pj in 1..5 (25 positions): cheap min-path
        for (int q = sw; q < 25; q += 2) {
            int Pi = 1 + q / 5, Pj = 1 + q % 5;   // wave-uniform
            uint32_t c[16];
#pragma unroll
            for (int r = 0; r < 4; ++r) {
                uint2 lo = *(const uint2*)&H1[(2 * Pi + r) * 16 + 2 * Pj];
                uint2 hi = *(const uint2*)&H1[(2 * Pi + r) * 16 + 2 * Pj + 2];
                c[r * 4 + 0] = lo.x; c[r * 4 + 1] = lo.y;
                c[r * 4 + 2] = hi.x; c[r * 4 + 3] = hi.y;
            }
            int mn = 100000;
#pragma unroll
            for (int a = 0; a < 2; ++a)
#pragma unroll
                for (int bb = 0; bb < 2; ++bb) {
                    int s = 0;
#pragma unroll
                    for (int kh = 0; kh < 3; ++kh)
#pragma unroll
                        for (int kw = 0; kw < 3; ++kw)
                            s += __popc(c[(a + kh) * 4 + (bb + kw)] ^ w2r[kh * 3 + kw]);
                    mn = imin2(mn, s);
                }
            uint64_t bal = __ballot(mn <= tle2);
            if (lane == 0) {
                uint2 wv = make_uint2((uint32_t)bal, (uint32_t)(bal >> 32));
                *(uint2*)&H2[((Pi + 1) * 9 + (Pj + 1)) * 2] = wv;
            }
        }
        // border pooled (24): uniform popcount + pattern correction (LDS)
        for (int bp = sw; bp < 24; bp += 2) {
            int Pi, Pj;
            if (bp < 7)       { Pi = 0; Pj = bp; }
            else if (bp < 14) { Pi = 6; Pj = bp - 7; }
            else if (bp < 19) { Pi = bp - 14 + 1; Pj = 0; }
            else              { Pi = bp - 19 + 1; Pj = 6; }
            uint32_t c[16];
#pragma unroll
            for (int r = 0; r < 4; ++r) {
                uint2 lo = *(const uint2*)&H1[(2 * Pi + r) * 16 + 2 * Pj];
                uint2 hi = *(const uint2*)&H1[(2 * Pi + r) * 16 + 2 * Pj + 2];
                c[r * 4 + 0] = lo.x; c[r * 4 + 1] = lo.y;
                c[r * 4 + 2] = hi.x; c[r * 4 + 3] = hi.y;
            }
            int best = -100000;
#pragma unroll
            for (int a = 0; a < 2; ++a)
#pragma unroll
                for (int bb = 0; bb < 2; ++bb) {
                    int s = 0;
#pragma unroll
                    for (int kh = 0; kh < 3; ++kh)
#pragma unroll
                        for (int kw = 0; kw < 3; ++kw)
                            s += __popc(c[(a + kh) * 4 + (bb + kw)] ^ w2r[kh * 3 + kw]);
                    int i = 2 * Pi + a, j = 2 * Pj + bb;
                    int pat = (i == 0 ? 1 : 0) | (i == 13 ? 2 : 0) |
                              (j == 0 ? 4 : 0) | (j == 13 ? 8 : 0);
                    int D = 288 - 2 * s + SH[pat * 64 + lane];
                    best = imax2(best, D);
                }
            uint64_t bal = __ballot(best >= tge2);
            if (lane == 0) {
                uint2 wv = make_uint2((uint32_t)bal, (uint32_t)(bal >> 32));
                *(uint2*)&H2[((Pi + 1) * 9 + (Pj + 1)) * 2] = wv;
            }
        }
    }
    __syncthreads();

    // ---- conv3 (64->16) + bias + relu -> h3T[k][img] ----
    {
        const uint32_t* H2 = (const uint32_t*)W + 288;
        int oc = lane & 15, sub = lane >> 4;
        uint32_t w3r[18];
#pragma unroll
        for (int k = 0; k < 18; ++k) w3r[k] = utab[TW_W3 + oc * 18 + k];
        float bias3 = b3[oc];
        const int gbeg = sw ? 6 : 0, gend = sw ? 13 : 6;
        for (int g = gbeg; g < gend; ++g) {
            int pos = g * 4 + sub;
            bool act = pos < 49;
            int pp = act ? pos : 0;
            int Pi = pp / 7, Pj = pp % 7;
            int s = 0;
#pragma unroll
            for (int kh = 0; kh < 3; ++kh)
#pragma unroll
                for (int kw = 0; kw < 3; ++kw) {
                    uint2 hv = *(const uint2*)&H2[((Pi + kh) * 9 + (Pj + kw)) * 2];
                    s += __popc(hv.x ^ w3r[(kh * 3 + kw) * 2]) +
                         __popc(hv.y ^ w3r[(kh * 3 + kw) * 2 + 1]);
                }
            int pat = (Pi == 0 ? 1 : 0) | (Pi == 6 ? 2 : 0) |
                      (Pj == 0 ? 4 : 0) | (Pj == 6 ? 8 : 0);
            int D = 576 - 2 * s + SH[1024 + pat * 16 + oc];
            float h = (float)D + bias3;
            h = h > 0.f ? h : 0.f;
            if (act) h3T[(oc * 49 + pp) * 4096 + img] = h;
        }
    }
}

// ---------------- FC1: 64img x 32n tile, grid 512 = 2 blocks/CU -------------
// KC=40 double-buffered gload_lds; raw s_barrier + counted vmcnt so prefetch
// stays in flight across barriers. 15 segs/chunk: A=10, B=5 (waves issue 4/4/4/3
// loads -> vmcnt(3) safely covers the worst case).
__global__ __launch_bounds__(256) void fc1_gemm(
    const float* __restrict__ aT,    // h3T [800][4096]
    const float* __restrict__ bT,    // fc1_wT [800][256]
    const float* __restrict__ bias,
    float* __restrict__ oT) {        // h1T [256][4096]
    const int KC = 40;               // 20 chunks of 40
    __shared__ float As[2][KC * 64];
    __shared__ float Bs[2][KC * 32];
    const int t = threadIdx.x;
    const int lane = t & 63, wid = t >> 6;
    const int tx = t & 15, ty = t >> 4;
    const int img0 = blockIdx.x * 64;
    const int n0 = blockIdx.y * 32;
    float acc[4][2] = {{0.f}};

    // A: 10 segs of 1KB (4 rows x 64 f); B: 5 segs of 1KB (8 rows x 32 f)
    auto stage = [&](int buf, int kc) {
        for (int s = wid; s < 15; s += 4) {
            if (s < 10) {
                int kk = s * 4 + (lane >> 4);
                int c = (lane & 15) * 4;
                gload16(&aT[(kc + kk) * 4096 + img0 + c], &As[buf][s * 256], lane);
            } else {
                int seg = s - 10;
                int kk = seg * 8 + (lane >> 3);
                int c = (lane & 7) * 4;
                gload16(&bT[(kc + kk) * 256 + n0 + c], &Bs[buf][seg * 256], lane);
            }
        }
    };

    stage(0, 0);
    asm volatile("s_waitcnt vmcnt(0)" ::: "memory");
    __builtin_amdgcn_s_barrier();
    for (int ch = 0; ch < 20; ++ch) {
        int buf = ch & 1;
        if (ch < 19) {
            stage(buf ^ 1, (ch + 1) * KC);   // <=4 more in flight per wave
            asm volatile("s_waitcnt vmcnt(3)" ::: "memory");  // own ch loads done
        } else {
            asm volatile("s_waitcnt vmcnt(0)" ::: "memory");
        }
        __builtin_amdgcn_s_barrier();         // everyone's ch loads landed
        const float* A = As[buf];
        const float* B = Bs[buf];
#pragma unroll 8
        for (int kk = 0; kk < KC; ++kk) {
            float4 a = *(const float4*)&A[kk * 64 + ty * 4];
            float2 b = *(const float2*)&B[kk * 32 + tx * 2];
            acc[0][0] += a.x * b.x; acc[0][1] += a.x * b.y;
            acc[1][0] += a.y * b.x; acc[1][1] += a.y * b.y;
            acc[2][0] += a.z * b.x; acc[2][1] += a.z * b.y;
            acc[3][0] += a.w * b.x; acc[3][1] += a.w * b.y;
        }
        __builtin_amdgcn_s_barrier();         // all waves done reading buf
    }
#pragma unroll
    for (int j = 0; j < 2; ++j) {
        int n = n0 + tx * 2 + j;
        float bj = bias[n];
        float4 ov;
        ov.x = acc[0][j] + bj; ov.x = ov.x > 0.f ? ov.x : 0.f;
        ov.y = acc[1][j] + bj; ov.y = ov.y > 0.f ? ov.y : 0.f;
        ov.z = acc[2][j] + bj; ov.z = ov.z > 0.f ? ov.z : 0.f;
        ov.w = acc[3][j] + bj; ov.w = ov.w > 0.f ? ov.w : 0.f;
        *(float4*)&oT[n * 4096 + img0 + ty * 4] = ov;
    }
}

// ---------------- FC2: [4096x256] x [256x128] -> relu -> h2T ----------------
// 64x32 tile, KC=64, 2-phase async pipeline (r5 form, measured-good)
__global__ __launch_bounds__(256) void fc2_gemm(
    const float* __restrict__ aT,    // h1T [256][4096]
    const float* __restrict__ bT,    // fc2_wT [256][128]
    const float* __restrict__ bias,
    float* __restrict__ oT) {        // h2T [128][4096]
    const int KC = 64;               // 4 chunks of 64
    __shared__ float As[2][KC * 64];
    __shared__ float Bs[2][KC * 32];
    const int t = threadIdx.x;
    const int lane = t & 63, wid = t >> 6;
    const int tx = t & 15, ty = t >> 4;
    const int img0 = blockIdx.x * 64;
    const int n0 = blockIdx.y * 32;
    float acc[4][2] = {{0.f}};

    // A: 64x64 = 16 segs; B: 64x32 = 8 segs (each seg 1KB); 6 gloads/wave
    auto stage = [&](int buf, int kc) {
        for (int s = wid; s < 24; s += 4) {
            if (s < 16) {
                int kk = s * 4 + (lane >> 4);
                int c = (lane & 15) * 4;
                gload16(&aT[(kc + kk) * 4096 + img0 + c], &As[buf][s * 256], lane);
            } else {
                int seg = s - 16;
                int kk = seg * 8 + (lane >> 3);
                int c = (lane & 7) * 4;
                gload16(&bT[(kc + kk) * 128 + n0 + c], &Bs[buf][seg * 256], lane);
            }
        }
    };

    stage(0, 0);
    asm volatile("s_waitcnt vmcnt(0)" ::: "memory");
    __builtin_amdgcn_s_barrier();
    for (int ch = 0; ch < 4; ++ch) {
        int buf = ch & 1;
        if (ch < 3) {
            stage(buf ^ 1, (ch + 1) * KC);
            asm volatile("s_waitcnt vmcnt(6)" ::: "memory");
        } else {
            asm volatile("s_waitcnt vmcnt(0)" ::: "memory");
        }
        __builtin_amdgcn_s_barrier();
        const float* A = As[buf];
        const float* B = Bs[buf];
#pragma unroll 8
        for (int kk = 0; kk < KC; ++kk) {
            float4 a = *(const float4*)&A[kk * 64 + ty * 4];
            float2 b = *(const float2*)&B[kk * 32 + tx * 2];
            acc[0][0] += a.x * b.x; acc[0][1] += a.x * b.y;
            acc[1][0] += a.y * b.x; acc[1][1] += a.y * b.y;
            acc[2][0] += a.z * b.x; acc[2][1] += a.z * b.y;
            acc[3][0] += a.w * b.x; acc[3][1] += a.w * b.y;
        }
        __builtin_amdgcn_s_barrier();
    }
#pragma unroll
    for (int j = 0; j < 2; ++j) {
        int n = n0 + tx * 2 + j;
        float bj = bias[n];
        float4 ov;
        ov.x = acc[0][j] + bj; ov.x = ov.x > 0.f ? ov.x : 0.f;
        ov.y = acc[1][j] + bj; ov.y = ov.y > 0.f ? ov.y : 0.f;
        ov.z = acc[2][j] + bj; ov.z = ov.z > 0.f ? ov.z : 0.f;
        ov.w = acc[3][j] + bj; ov.w = ov.w > 0.f ? ov.w : 0.f;
        *(float4*)&oT[n * 4096 + img0 + ty * 4] = ov;
    }
}

// ---------------- FC3: [4096x128] x [128x10] -> out -------------------------
__global__ __launch_bounds__(256) void fc3_gemm(
    const float* __restrict__ aT,    // h2T [128][4096]
    const float* __restrict__ w,     // fc3_w [10][128]
    const float* __restrict__ bias,
    float* __restrict__ out) {       // [4096][10]
    int id = blockIdx.x * 256 + threadIdx.x;   // 40960
    int n = id >> 12, img = id & 4095;
    const float* wr = w + n * 128;
    float a0 = 0.f, a1 = 0.f, a2 = 0.f, a3 = 0.f;
#pragma unroll 8
    for (int k = 0; k < 128; k += 4) {
        a0 += aT[(k + 0) * 4096 + img] * wr[k + 0];
        a1 += aT[(k + 1) * 4096 + img] * wr[k + 1];
        a2 += aT[(k + 2) * 4096 + img] * wr[k + 2];
        a3 += aT[(k + 3) * 4096 + img] * wr[k + 3];
    }
    out[img * 10 + n] = (a0 + a1) + (a2 + a3) + bias[n];
}

extern "C" void kernel_launch(void* const* d_in, const int* in_sizes, int n_in,
                              void* d_out, int out_size, void* d_ws, size_t ws_size,
                              hipStream_t stream) {
    const float* x     = (const float*)d_in[0];
    const float* w1    = (const float*)d_in[1];
    const float* b1    = (const float*)d_in[2];
    const float* w2    = (const float*)d_in[3];
    const float* b2    = (const float*)d_in[4];
    const float* w3    = (const float*)d_in[5];
    const float* b3    = (const float*)d_in[6];
    const float* fc1_w = (const float*)d_in[7];
    const float* fc1_b = (const float*)d_in[8];
    const float* fc2_w = (const float*)d_in[9];
    const float* fc2_b = (const float*)d_in[10];
    const float* fc3_w = (const float*)d_in[11];
    const float* fc3_b = (const float*)d_in[12];
    float* out = (float*)d_out;

    const int B = in_sizes[0] / 784;  // 4096
    char* ws = (char*)d_ws;
    float* w1T = (float*)(ws + OFF_W1T);
    float* w2T = (float*)(ws + OFF_W2T);
    float* h3T = (float*)(ws + OFF_H3T);
    float* h1T = (float*)(ws + OFF_H1T);
    float* h2T = (float*)(ws + OFF_H2T);
    int* tab = (int*)(ws + OFF_H2T);  // tables alias h2T (disjoint lifetime)

    hipLaunchKernelGGL(prep, dim3(61), dim3(256), 0, stream,
                       w1, b1, w2, b2, w3, fc1_w, fc2_w, tab, w1T, w2T);
    hipLaunchKernelGGL(conv_stack, dim3(B / 4), dim3(512), 0, stream,
                       x, b3, tab, h3T);
    hipLaunchKernelGGL(fc1_gemm, dim3(B / 64, 8), dim3(256), 0, stream,
                       h3T, w1T, fc1_b, h1T);
    hipLaunchKernelGGL(fc2_gemm, dim3(B / 64, 4), dim3(256), 0, stream,
                       h1T, w2T, fc2_b, h2T);
    hipLaunchKernelGGL(fc3_gemm, dim3(B * 10 / 256), dim3(256), 0, stream,
                       h2T, fc3_w, fc3_b, out);
}